// Round 3
// baseline (220.395 us; speedup 1.0000x reference)
//
#include <hip/hip_runtime.h>

// CompactPiecewiseLinearEmbeddings: out[n,f,:] = C[f][k] + t*(C[f][k+1]-C[f][k])
// where k = #{j in [1,47] : edges[f][j] <= x[n,f]}, t = (x - edges[f][k]) / width[f][k],
// C[f][j] = bias[f] + sum_{b<j} W[f][b][:]   (sorted boundaries => h = [1..1, t, 0..0])
//
// R3: flatten the search. Old: 6 serial LDS probes (~720 cyc dependent chain).
// New: coarse level {E[8m]} hoisted to REGISTERS (loop-invariant per thread),
// fine level = two aligned ds_read_b128 of E[k_hi..k_hi+7] + compare-count.
// One thread per (n,f) (no duplicated search); stores are 2x dwordx4 per
// thread -- same-wave adjacent halves merge in L2 (R2 disproved the RMW theory).

#define NN 16384
#define FF 256
#define BB 48
#define DD 8

#define FT 16              // features per block
#define NSPLIT 64          // n-splits
#define NPB (NN / NSPLIT)  // 256 rows per block

#define ESTR 52            // sEv per-feature stride (floats); 16B-mult, f/f+8 2-way banks (free)
#define RSTR 48            // sR stride
#define CSTR 396           // sC stride = 49*8+4; 16B-mult

__global__ __launch_bounds__(256, 4)
void cple_kernel(const float* __restrict__ X,
                 const float* __restrict__ Edg,
                 const float* __restrict__ Wid,
                 const float* __restrict__ W,
                 const float* __restrict__ Bias,
                 float* __restrict__ Out)
{
    __shared__ float sEv[FT * ESTR];  // edges [f][j=0..47], contiguous per feature
    __shared__ float sR [FT * RSTR];  // 1/width [f][j]
    __shared__ float sC [FT * CSTR];  // cumulative W + bias, [f][j=0..48][d]

    const int tid = threadIdx.x;
    const int f0  = blockIdx.x * FT;
    const int ns  = blockIdx.y;

    // --- stage edges [f][0..47] (global rows are contiguous -> float4 copy) ---
    if (tid < FT * BB / 4) {  // 192 float4
        const float4* E4 = (const float4*)(Edg + (size_t)f0 * BB);
        float4 v = E4[tid];
        int f = tid / 12, j4 = tid % 12;
        *(float4*)&sEv[f * ESTR + j4 * 4] = v;
    }
    // --- stage reciprocal widths (coalesced) ---
    for (int idx = tid; idx < FT * BB; idx += 256) {
        int f = idx / BB, j = idx - f * BB;
        sR[f * RSTR + j] = 1.0f / Wid[(size_t)f0 * BB + idx];
    }
    // --- stage W tile into sC at [f][b+1][d] (contiguous 6144-float chunk) ---
    {
        const float4* Wt4 = (const float4*)(W + (size_t)f0 * BB * DD);
        for (int idx4 = tid; idx4 < FT * BB * DD / 4; idx4 += 256) {
            float4 v = Wt4[idx4];
            int idx = idx4 * 4;
            int f   = idx / (BB * DD);
            int rem = idx - f * (BB * DD);
            float* dst = &sC[f * CSTR + DD + rem];  // [f][(b=rem>>3)+1][d=rem&7]
            dst[0] = v.x; dst[1] = v.y; dst[2] = v.z; dst[3] = v.w;
        }
    }
    __syncthreads();

    // --- in-place inclusive scan: C[f][j][d] = bias + sum_{b<j} W[f][b][d] ---
    if (tid < FT * DD) {
        int f = tid >> 3, d = tid & 7;
        float acc = Bias[(size_t)(f0 + f) * DD + d];
        float* c = &sC[f * CSTR + d];
        c[0] = acc;
        #pragma unroll
        for (int b = 1; b <= BB; ++b) {
            acc += c[b * DD];   // holds W[f][b-1][d]
            c[b * DD] = acc;
        }
    }
    __syncthreads();

    // --- main loop: one thread per (n,f); 16 features x 16 rows per pass ---
    const int f_l = tid & 15;
    const int n_l = tid >> 4;
    const float* eF = &sEv[f_l * ESTR];
    const float* rF = &sR [f_l * RSTR];
    const float* cF = &sC [f_l * CSTR];
    const float* xp = X + (f0 + f_l);
    float* op = Out + (size_t)(f0 + f_l) * DD;

    // coarse search level: loop-invariant -> registers (read once)
    const float c8  = eF[8],  c16 = eF[16], c24 = eF[24];
    const float c32 = eF[32], c40 = eF[40];

    const int n0 = ns * NPB + n_l;
    #pragma unroll 4
    for (int i = 0; i < NPB / 16; ++i) {
        int n = n0 + i * 16;
        float x = xp[(size_t)n * FF];

        // coarse: k_hi = 8 * #{coarse edges <= x}  (pure VALU, no LDS)
        int k = 0;
        k += (x >= c8)  ? 8 : 0;
        k += (x >= c16) ? 8 : 0;
        k += (x >= c24) ? 8 : 0;
        k += (x >= c32) ? 8 : 0;
        k += (x >= c40) ? 8 : 0;

        // fine: E[k_hi .. k_hi+7], two aligned b128 reads, compare-count
        float4 fa = *(const float4*)(eF + k);
        float4 fb = *(const float4*)(eF + k + 4);
        k += (x >= fa.y) + (x >= fa.z) + (x >= fa.w)
           + (x >= fb.x) + (x >= fb.y) + (x >= fb.z) + (x >= fb.w);

        // gather round: e_k, r_k, C[k], C[k+1] (issued together)
        float t = (x - eF[k]) * rF[k];
        const float* cK = cF + k * DD;
        float4 l0 = *(const float4*)(cK);
        float4 l1 = *(const float4*)(cK + 4);
        float4 h0 = *(const float4*)(cK + 8);
        float4 h1 = *(const float4*)(cK + 12);

        float4 o0, o1;
        o0.x = fmaf(t, h0.x - l0.x, l0.x);
        o0.y = fmaf(t, h0.y - l0.y, l0.y);
        o0.z = fmaf(t, h0.z - l0.z, l0.z);
        o0.w = fmaf(t, h0.w - l0.w, l0.w);
        o1.x = fmaf(t, h1.x - l1.x, l1.x);
        o1.y = fmaf(t, h1.y - l1.y, l1.y);
        o1.z = fmaf(t, h1.z - l1.z, l1.z);
        o1.w = fmaf(t, h1.w - l1.w, l1.w);

        float4* o = (float4*)(op + (size_t)n * (FF * DD));
        o[0] = o0;  // same-wave adjacent halves of each 64B line merge in L2
        o[1] = o1;
    }
}

extern "C" void kernel_launch(void* const* d_in, const int* in_sizes, int n_in,
                              void* d_out, int out_size, void* d_ws, size_t ws_size,
                              hipStream_t stream) {
    const float* x     = (const float*)d_in[0];
    const float* edges = (const float*)d_in[1];
    const float* width = (const float*)d_in[2];
    const float* W     = (const float*)d_in[3];
    const float* b     = (const float*)d_in[4];
    float* out = (float*)d_out;

    dim3 grid(FF / FT, NSPLIT);
    cple_kernel<<<grid, 256, 0, stream>>>(x, edges, width, W, b, out);
}

// Round 4
// 162.839 us; speedup vs baseline: 1.3535x; 1.3535x over previous
//
#include <hip/hip_runtime.h>

// CompactPiecewiseLinearEmbeddings: out[n,f,:] = C[f][k] + t*(C[f][k+1]-C[f][k])
// where k = #{j in [1,47] : edges[f][j] <= x[n,f]}, t = (x - edges[f][k]) / width[f][k],
// C[f][j] = bias[f] + sum_{b<j} W[f][b][:]   (sorted boundaries => h = [1..1, t, 0..0])
//
// R4: latency attack. R3 was latency-bound (VALU 6.6%, occ 30%, 7.3M LDS
// conflict cycles). Changes: FT 16->8 (17.5KB LDS, 2048 blocks, no f/f+8
// bank aliasing), coarse search level in REGISTERS (11 regs, pure VALU),
// fine = one aligned b128 + 3 cmps, gather = b64 (r,-e*r) + 4x b128 C in one
// round, 2-row ILP + explicit x prefetch, reg-chunked prefix scan.

#define NN 16384
#define FF 256
#define BB 48
#define DD 8

#define FT 8               // features per block
#define NSPLIT 64          // n-splits
#define NPB (NN / NSPLIT)  // 256 rows per block

#define ESTR 52            // sE stride: 16B-mult, 20f mod 32 all-distinct over f=0..7
#define RASTR 100          // sRA stride (floats): 8B-mult, 4f mod 32 all-distinct
#define CSTR 396           // sC stride: 16B-mult, 12f mod 32 all-distinct

__global__ __launch_bounds__(256, 6)
void cple_kernel(const float* __restrict__ X,
                 const float* __restrict__ Edg,
                 const float* __restrict__ Wid,
                 const float* __restrict__ W,
                 const float* __restrict__ Bias,
                 float* __restrict__ Out)
{
    __shared__ float sE [FT * ESTR];   // edges [f][j=0..47]
    __shared__ float sRA[FT * RASTR];  // [f][j] -> (r_j, -e_j*r_j) pairs
    __shared__ float sC [FT * CSTR];   // cumulative W + bias, [f][j=0..48][d]

    const int tid = threadIdx.x;
    const int f0  = blockIdx.x * FT;
    const int ns  = blockIdx.y;

    // --- stage edges [f][0..47] (96 float4) ---
    if (tid < FT * BB / 4) {
        const float4* E4 = (const float4*)(Edg + (size_t)f0 * BB);
        float4 v = E4[tid];
        int f = tid / 12, j4 = tid % 12;
        *(float4*)&sE[f * ESTR + j4 * 4] = v;
    }
    // --- stage (r, -e*r) pairs ---
    for (int idx = tid; idx < FT * BB; idx += 256) {
        int f = idx / BB, j = idx - f * BB;
        float e = Edg[(size_t)f0 * BB + idx];
        float w = Wid[(size_t)f0 * BB + idx];
        float r = 1.0f / w;
        sRA[f * RASTR + 2 * j]     = r;
        sRA[f * RASTR + 2 * j + 1] = -e * r;
    }
    // --- stage W tile into sC at [f][b+1][d] (768 float4, 3 per thread) ---
    {
        const float4* Wt4 = (const float4*)(W + (size_t)f0 * BB * DD);
        #pragma unroll
        for (int q = 0; q < 3; ++q) {
            int idx4 = tid + q * 256;
            float4 v = Wt4[idx4];
            int idx = idx4 * 4;
            int f   = idx / (BB * DD);
            int rem = idx - f * (BB * DD);
            *(float4*)&sC[f * CSTR + DD + rem] = v;
        }
    }
    __syncthreads();

    // --- coarse search level -> registers (sE ready; overlaps with scan) ---
    const int f_l = tid & 7;
    const int n_l = tid >> 3;                 // 0..31
    const float* eF  = &sE [f_l * ESTR];
    const float* raF = &sRA[f_l * RASTR];
    const float* cF  = &sC [f_l * CSTR];
    float c4[11];
    #pragma unroll
    for (int m = 0; m < 11; ++m) c4[m] = eF[4 * (m + 1)];

    // --- prefix scan: C[f][j][d] = bias + sum_{b<j} W[f][b][d] (reg-chunked) ---
    if (tid < FT * DD) {
        int f = tid >> 3, d = tid & 7;
        float* c = &sC[f * CSTR + d];
        float acc = Bias[(size_t)(f0 + f) * DD + d];
        c[0] = acc;
        #pragma unroll
        for (int ch = 0; ch < 3; ++ch) {
            float w[16];
            #pragma unroll
            for (int j = 0; j < 16; ++j) w[j] = c[(ch * 16 + j + 1) * DD];
            #pragma unroll
            for (int j = 0; j < 16; ++j) { acc += w[j]; c[(ch * 16 + j + 1) * DD] = acc; }
        }
    }
    __syncthreads();

    // --- main loop: 8 features x 32 rows per pass, 2 rows/thread/iter ---
    const float* xp = X + (f0 + f_l);
    float* op = Out + (size_t)(f0 + f_l) * DD;

    const int nbase = ns * NPB + n_l;
    float xa = xp[(size_t)nbase * FF];
    float xb = xp[(size_t)(nbase + 128) * FF];

    #pragma unroll
    for (int i = 0; i < 4; ++i) {
        int na = nbase + i * 32;
        int nb = na + 128;
        float xA = xa, xB = xb;
        if (i < 3) {   // prefetch next pair (hides HBM-cold x latency)
            xa = xp[(size_t)(na + 32) * FF];
            xb = xp[(size_t)(na + 160) * FF];
        }

        // coarse: group g = #{m: x >= E[4m]}, k4 = 4g (pure VALU, registers)
        int ga = 0, gb = 0;
        #pragma unroll
        for (int m = 0; m < 11; ++m) {
            ga += (xA >= c4[m]) ? 1 : 0;
            gb += (xB >= c4[m]) ? 1 : 0;
        }
        int k4a = ga * 4, k4b = gb * 4;

        // fine: one aligned b128 of E[k4..k4+3], count 3
        float4 ea = *(const float4*)(eF + k4a);
        float4 eb = *(const float4*)(eF + k4b);
        int ka = k4a + (xA >= ea.y) + (xA >= ea.z) + (xA >= ea.w);
        int kb = k4b + (xB >= eb.y) + (xB >= eb.z) + (xB >= eb.w);

        // gather round: (r,-e*r) b64 + C[k],C[k+1] 4x b128 (one latency round)
        float2 raA = *(const float2*)(raF + 2 * ka);
        float2 raB = *(const float2*)(raF + 2 * kb);
        const float* cKa = cF + ka * DD;
        const float* cKb = cF + kb * DD;
        float4 la0 = *(const float4*)(cKa);
        float4 la1 = *(const float4*)(cKa + 4);
        float4 ha0 = *(const float4*)(cKa + 8);
        float4 ha1 = *(const float4*)(cKa + 12);
        float4 lb0 = *(const float4*)(cKb);
        float4 lb1 = *(const float4*)(cKb + 4);
        float4 hb0 = *(const float4*)(cKb + 8);
        float4 hb1 = *(const float4*)(cKb + 12);

        float ta = fmaf(xA, raA.x, raA.y);
        float tb = fmaf(xB, raB.x, raB.y);

        float4 oa0, oa1, ob0, ob1;
        oa0.x = fmaf(ta, ha0.x - la0.x, la0.x);
        oa0.y = fmaf(ta, ha0.y - la0.y, la0.y);
        oa0.z = fmaf(ta, ha0.z - la0.z, la0.z);
        oa0.w = fmaf(ta, ha0.w - la0.w, la0.w);
        oa1.x = fmaf(ta, ha1.x - la1.x, la1.x);
        oa1.y = fmaf(ta, ha1.y - la1.y, la1.y);
        oa1.z = fmaf(ta, ha1.z - la1.z, la1.z);
        oa1.w = fmaf(ta, ha1.w - la1.w, la1.w);
        ob0.x = fmaf(tb, hb0.x - lb0.x, lb0.x);
        ob0.y = fmaf(tb, hb0.y - lb0.y, lb0.y);
        ob0.z = fmaf(tb, hb0.z - lb0.z, lb0.z);
        ob0.w = fmaf(tb, hb0.w - lb0.w, lb0.w);
        ob1.x = fmaf(tb, hb1.x - lb1.x, lb1.x);
        ob1.y = fmaf(tb, hb1.y - lb1.y, lb1.y);
        ob1.z = fmaf(tb, hb1.z - lb1.z, lb1.z);
        ob1.w = fmaf(tb, hb1.w - lb1.w, lb1.w);

        float4* oA = (float4*)(op + (size_t)na * (FF * DD));
        float4* oB = (float4*)(op + (size_t)nb * (FF * DD));
        oA[0] = oa0; oA[1] = oa1;
        oB[0] = ob0; oB[1] = ob1;
    }
}

extern "C" void kernel_launch(void* const* d_in, const int* in_sizes, int n_in,
                              void* d_out, int out_size, void* d_ws, size_t ws_size,
                              hipStream_t stream) {
    const float* x     = (const float*)d_in[0];
    const float* edges = (const float*)d_in[1];
    const float* width = (const float*)d_in[2];
    const float* W     = (const float*)d_in[3];
    const float* b     = (const float*)d_in[4];
    float* out = (float*)d_out;

    dim3 grid(FF / FT, NSPLIT);
    cple_kernel<<<grid, 256, 0, stream>>>(x, edges, width, W, b, out);
}